// Round 7
// baseline (1566.007 us; speedup 1.0000x reference)
//
#include <hip/hip_runtime.h>
#include <stdint.h>

typedef __attribute__((ext_vector_type(8))) short bf8_t;   // 8 bf16 (4 VGPRs) MFMA A/B frag
typedef __attribute__((ext_vector_type(4))) float f4_t;    // MFMA C/D frag

#define DEVI static __device__ __forceinline__

// fp32 -> bf16 round-to-nearest-even
DEVI unsigned short f2b(float f) {
  unsigned u = __builtin_bit_cast(unsigned, f);
  u += 0x7fffu + ((u >> 16) & 1u);
  return (unsigned short)(u >> 16);
}

// ---------------------------------------------------------------- cast kernel (with optional scale fold)
__global__ void cast_bf16_k(const float* __restrict__ src, ushort* __restrict__ dst, int n4, float scale) {
  int i = blockIdx.x * 256 + threadIdx.x;
  if (i >= n4) return;
  float4 v = reinterpret_cast<const float4*>(src)[i];
  ushort4 o;
  o.x = f2b(v.x * scale); o.y = f2b(v.y * scale); o.z = f2b(v.z * scale); o.w = f2b(v.w * scale);
  reinterpret_cast<ushort4*>(dst)[i] = o;
}

// ---------------------------------------------------------------- mask bit-pack
// mask int32 (b,n,m) in {0,1}  ->  packed ushort words: word i covers cols i*16..i*16+15,
// bit j = mask[col i*16+j]. Total 4*2048*128 ushorts = 2 MB (L2-resident in attn).
__global__ void mask_pack_k(const int* __restrict__ mask, ushort* __restrict__ mp, int nwords) {
  int i = blockIdx.x * 256 + threadIdx.x;
  if (i >= nwords) return;
  const int4* src = reinterpret_cast<const int4*>(mask + (size_t)i * 16);
  unsigned v = 0;
#pragma unroll
  for (int j = 0; j < 4; j++) {
    int4 m = src[j];
    v |= ((unsigned)(m.x & 1) << (j * 4 + 0));
    v |= ((unsigned)(m.y & 1) << (j * 4 + 1));
    v |= ((unsigned)(m.z & 1) << (j * 4 + 2));
    v |= ((unsigned)(m.w & 1) << (j * 4 + 3));
  }
  mp[i] = (ushort)v;
}

// ---------------------------------------------------------------- GEMM: C[n][o] = sum_d A[n][d]*W[o][d] + bias[o]*bscale
// A: 8192x1024 bf16 row-major, W: 1024x1024 bf16 row-major (torch Linear weight).
// MODE 0: out bf16 row-major (8192x1024)
// MODE 1: out bf16 transposed per batch: Vt[(b*1024 + o)*2048 + n_local]
// MODE 2: out fp32 row-major (8192x1024)
template<int MODE>
__global__ __launch_bounds__(256, 3) void gemm_bt(const ushort* __restrict__ A,
                                                  const ushort* __restrict__ W,
                                                  const float* __restrict__ bias,
                                                  void* __restrict__ outp, float bscale) {
  // XOR-swizzled LDS tiles: row stride 64 bf16 (128B), unit (16B) u stored at u ^ (row&7)
  __shared__ ushort As[128 * 64];
  __shared__ ushort Ws[128 * 64];
  const int t = threadIdx.x;
  const int tileCol = blockIdx.x & 7;   // 1024/128 col tiles — fastest so A-tile reused by consecutive blocks
  const int tileRow = blockIdx.x >> 3;  // 8192/128 row tiles
  const int rowBase = tileRow * 128;
  const int colBase = tileCol * 128;

  const int r32 = t >> 3;  // 0..31 staging row
  const int cu = t & 7;    // 16B unit within 128B row
  const int w = t >> 6;
  const int lane = t & 63;
  const int q = lane >> 4;
  const int c = lane & 15;
  const int wr = (w >> 1) * 64;
  const int wc = (w & 1) * 64;

  f4_t acc[4][4];
#pragma unroll
  for (int i = 0; i < 4; i++)
#pragma unroll
    for (int j = 0; j < 4; j++) acc[i][j] = (f4_t){0.f, 0.f, 0.f, 0.f};

  for (int k0 = 0; k0 < 1024; k0 += 64) {
#pragma unroll
    for (int rs = 0; rs < 4; rs++) {
      int r = rs * 32 + r32;
      int4 va = *reinterpret_cast<const int4*>(A + (size_t)(rowBase + r) * 1024 + k0 + cu * 8);
      int4 vw = *reinterpret_cast<const int4*>(W + (size_t)(colBase + r) * 1024 + k0 + cu * 8);
      *reinterpret_cast<int4*>(&As[r * 64 + ((cu ^ (r & 7)) << 3)]) = va;
      *reinterpret_cast<int4*>(&Ws[r * 64 + ((cu ^ (r & 7)) << 3)]) = vw;
    }
    __syncthreads();
    bf8_t af[4][2], bfr[4][2];
#pragma unroll
    for (int i = 0; i < 4; i++) {
      int ra = wr + i * 16 + c;
      int rb = wc + i * 16 + c;
#pragma unroll
      for (int s = 0; s < 2; s++) {
        af[i][s] = *reinterpret_cast<const bf8_t*>(&As[ra * 64 + (((s * 4 + q) ^ (ra & 7)) << 3)]);
        bfr[i][s] = *reinterpret_cast<const bf8_t*>(&Ws[rb * 64 + (((s * 4 + q) ^ (rb & 7)) << 3)]);
      }
    }
#pragma unroll
    for (int i = 0; i < 4; i++)
#pragma unroll
      for (int j = 0; j < 4; j++) {
        acc[i][j] = __builtin_amdgcn_mfma_f32_16x16x32_bf16(af[i][0], bfr[j][0], acc[i][j], 0, 0, 0);
        acc[i][j] = __builtin_amdgcn_mfma_f32_16x16x32_bf16(af[i][1], bfr[j][1], acc[i][j], 0, 0, 0);
      }
    __syncthreads();
  }

  // epilogue: D layout col=lane&15, row=(lane>>4)*4+reg  [measured m89/m91]
#pragma unroll
  for (int j = 0; j < 4; j++) {
    int col = colBase + wc + j * 16 + c;
    float bj = bias[col] * bscale;
#pragma unroll
    for (int i = 0; i < 4; i++) {
      int rbase = rowBase + wr + i * 16 + q * 4;
      if (MODE == 0) {
        ushort* out = (ushort*)outp;
#pragma unroll
        for (int reg = 0; reg < 4; reg++)
          out[(size_t)(rbase + reg) * 1024 + col] = f2b(acc[i][j][reg] + bj);
      } else if (MODE == 1) {
        ushort* out = (ushort*)outp;
        int bb = rbase >> 11;
        int nl = rbase & 2047;
        ushort4 v;
        v.x = f2b(acc[i][j][0] + bj);
        v.y = f2b(acc[i][j][1] + bj);
        v.z = f2b(acc[i][j][2] + bj);
        v.w = f2b(acc[i][j][3] + bj);
        *reinterpret_cast<ushort4*>(out + ((size_t)(bb * 1024 + col) * 2048 + nl)) = v;
      } else {
        float* out = (float*)outp;
#pragma unroll
        for (int reg = 0; reg < 4; reg++)
          out[(size_t)(rbase + reg) * 1024 + col] = acc[i][j][reg] + bj;
      }
    }
  }
}

// ---------------------------------------------------------------- fused attention (two-pass, RECOMPUTE, no fences)
// Block: one (b,h), 16 q-rows, 256 threads. 4 waves split m (512 cols each).
// Q comes PRE-SCALED by (1/sqrt(64))*log2(e), so exp2(s) is the softmax numerator directly.
// R3-R6 lesson: ANY scheme storing per-lane e-state for 512 cols (32-64 VGPRs) gets spilled
// to scratch by the allocator (0.3-1 GB of scratch traffic). So: RECOMPUTE. Pass 1 computes
// l = sum exp; pass 2 recomputes s and e (QK MFMA at 5% util, exp at 25% VALU — both free),
// writes beta = e/l, and feeds PV. NO __threadfence_block anywhere (R5: it lowers to
// s_waitcnt vmcnt(0) lgkmcnt(0), draining all in-flight loads per chunk = 95% stall; R6
// proved removal is correct — same-wave LDS ops are in-order, compiler orders may-alias Pb).
__global__ __launch_bounds__(256, 4) void attn_k(const ushort* __restrict__ Qb,
                                                 const ushort* __restrict__ Kb,
                                                 const ushort* __restrict__ Vt,
                                                 const ushort* __restrict__ Mp,
                                                 float* __restrict__ beta,
                                                 ushort* __restrict__ Cc) {
  __shared__ float lpart[4][16];
  __shared__ ushort Pb[4][16][40];   // per-wave P staging, stride 40 bf16 -> 2-way max on b128 reads
  __shared__ float Ow[4][16][68];    // O merge, stride 68 -> 2-way max

  // XCD-affine swizzle: head-pairs pinned to XCD so K/V stay L2-resident
  const int L = blockIdx.x;
  const int bh = (L >> 10) * 8 + (L & 7);  // 0..63
  const int qt = (L >> 3) & 127;
  const int b = bh >> 4;
  const int h = bh & 15;
  const int n0 = qt * 16;

  const int t = threadIdx.x;
  const int w = t >> 6;
  const int lane = t & 63;
  const int q = lane >> 4;
  const int c = lane & 15;

  const size_t qbase = ((size_t)(b * 2048 + n0 + c)) * 1024 + h * 64 + q * 8;
  bf8_t qa0 = *reinterpret_cast<const bf8_t*>(Qb + qbase);
  bf8_t qa1 = *reinterpret_cast<const bf8_t*>(Qb + qbase + 32);

  const int mBase = w * 512;
  const size_t kbase0 = ((size_t)(b * 2048 + mBase + c)) * 1024 + h * 64 + q * 8;
  const size_t vbase = ((size_t)(b * 1024 + h * 64 + c)) * 2048 + mBase + q * 8;
  // packed-mask base for this block's 16 rows + this wave's 512-col strip (32 words)
  const ushort* mpk = Mp + ((size_t)(b * 2048 + n0)) * 128 + (mBase >> 4);

  // ---- pass 1: denominators (no LDS, no fences -> fully pipelined)
  float ls[4] = {0.f, 0.f, 0.f, 0.f};
#pragma unroll
  for (int g = 0; g < 4; g++) {
    int4 mrow[4];
#pragma unroll
    for (int r = 0; r < 4; r++)
      mrow[r] = *reinterpret_cast<const int4*>(mpk + (size_t)(q * 4 + r) * 128 + g * 8);
#pragma unroll
    for (int mi = 0; mi < 8; mi++) {
      const int mb = g * 8 + mi;
      const ushort* kp = Kb + kbase0 + (size_t)mb * 16 * 1024;
      bf8_t k0 = *reinterpret_cast<const bf8_t*>(kp);
      bf8_t k1 = *reinterpret_cast<const bf8_t*>(kp + 32);
      f4_t s = (f4_t){0.f, 0.f, 0.f, 0.f};
      s = __builtin_amdgcn_mfma_f32_16x16x32_bf16(qa0, k0, s, 0, 0, 0);
      s = __builtin_amdgcn_mfma_f32_16x16x32_bf16(qa1, k1, s, 0, 0, 0);
#pragma unroll
      for (int reg = 0; reg < 4; reg++) {
        unsigned mword = (unsigned)((mi >> 1) == 0 ? mrow[reg].x
                                  : (mi >> 1) == 1 ? mrow[reg].y
                                  : (mi >> 1) == 2 ? mrow[reg].z
                                                   : mrow[reg].w);
        unsigned masked = (mword >> ((mi & 1) * 16 + c)) & 1u;
        float e = masked ? 0.f : __builtin_amdgcn_exp2f(s[reg]);
        ls[reg] += e;
      }
    }
  }

  // ---- row-sum reduce (16 lanes share a row-group) -> lpart -> linv
#pragma unroll
  for (int reg = 0; reg < 4; reg++) {
    ls[reg] += __shfl_xor(ls[reg], 1);
    ls[reg] += __shfl_xor(ls[reg], 2);
    ls[reg] += __shfl_xor(ls[reg], 4);
    ls[reg] += __shfl_xor(ls[reg], 8);
  }
  if (c == 0) {
#pragma unroll
    for (int reg = 0; reg < 4; reg++) lpart[w][q * 4 + reg] = ls[reg];
  }
  __syncthreads();
  float linv[4];
#pragma unroll
  for (int reg = 0; reg < 4; reg++) {
    int r = q * 4 + reg;
    linv[reg] = 1.0f / (lpart[0][r] + lpart[1][r] + lpart[2][r] + lpart[3][r]);
  }

  // ---- pass 2: recompute s,e; write beta; stage Pb; PV (no fences)
  f4_t o[4];
#pragma unroll
  for (int db = 0; db < 4; db++) o[db] = (f4_t){0.f, 0.f, 0.f, 0.f};

  float* betab = beta + ((size_t)(bh * 2048 + n0)) * 2048 + mBase + c;

#pragma unroll
  for (int g = 0; g < 4; g++) {
    int4 mrow[4];
#pragma unroll
    for (int r = 0; r < 4; r++)
      mrow[r] = *reinterpret_cast<const int4*>(mpk + (size_t)(q * 4 + r) * 128 + g * 8);
#pragma unroll
    for (int mi = 0; mi < 8; mi++) {
      const int mb = g * 8 + mi;
      const ushort* kp = Kb + kbase0 + (size_t)mb * 16 * 1024;
      bf8_t k0 = *reinterpret_cast<const bf8_t*>(kp);
      bf8_t k1 = *reinterpret_cast<const bf8_t*>(kp + 32);
      f4_t s = (f4_t){0.f, 0.f, 0.f, 0.f};
      s = __builtin_amdgcn_mfma_f32_16x16x32_bf16(qa0, k0, s, 0, 0, 0);
      s = __builtin_amdgcn_mfma_f32_16x16x32_bf16(qa1, k1, s, 0, 0, 0);
#pragma unroll
      for (int reg = 0; reg < 4; reg++) {
        unsigned mword = (unsigned)((mi >> 1) == 0 ? mrow[reg].x
                                  : (mi >> 1) == 1 ? mrow[reg].y
                                  : (mi >> 1) == 2 ? mrow[reg].z
                                                   : mrow[reg].w);
        unsigned masked = (mword >> ((mi & 1) * 16 + c)) & 1u;
        float e = masked ? 0.f : __builtin_amdgcn_exp2f(s[reg]);
        betab[(size_t)(q * 4 + reg) * 2048 + mb * 16] = e * linv[reg];
        Pb[w][q * 4 + reg][(mb & 1) * 16 + c] = f2b(e);
      }
      if (mb & 1) {
        // same-wave LDS in-order; compiler orders may-aliasing Pb accesses — no fence
        bf8_t pa = *reinterpret_cast<const bf8_t*>(&Pb[w][c][q * 8]);
        const int m0 = (mb & ~1) * 16;
#pragma unroll
        for (int db = 0; db < 4; db++) {
          bf8_t vf = *reinterpret_cast<const bf8_t*>(Vt + vbase + (size_t)db * 16 * 2048 + m0);
          o[db] = __builtin_amdgcn_mfma_f32_16x16x32_bf16(pa, vf, o[db], 0, 0, 0);
        }
      }
    }
  }

  // ---- merge O across waves (unnormalized partials), scale by 1/l, store concat bf16
#pragma unroll
  for (int db = 0; db < 4; db++)
#pragma unroll
    for (int reg = 0; reg < 4; reg++) Ow[w][q * 4 + reg][db * 16 + c] = o[db][reg];
  __syncthreads();
  {
    int r = t >> 4;
    int d0 = (t & 15) * 4;
    float lr = lpart[0][r] + lpart[1][r] + lpart[2][r] + lpart[3][r];
    float sl = 1.0f / lr;
    float4 s0 = *reinterpret_cast<const float4*>(&Ow[0][r][d0]);
    float4 s1 = *reinterpret_cast<const float4*>(&Ow[1][r][d0]);
    float4 s2 = *reinterpret_cast<const float4*>(&Ow[2][r][d0]);
    float4 s3 = *reinterpret_cast<const float4*>(&Ow[3][r][d0]);
    ushort4 ov;
    ov.x = f2b((s0.x + s1.x + s2.x + s3.x) * sl);
    ov.y = f2b((s0.y + s1.y + s2.y + s3.y) * sl);
    ov.z = f2b((s0.z + s1.z + s2.z + s3.z) * sl);
    ov.w = f2b((s0.w + s1.w + s2.w + s3.w) * sl);
    *reinterpret_cast<ushort4*>(Cc + ((size_t)(b * 2048 + n0 + r)) * 1024 + h * 64 + d0) = ov;
  }
}

// ---------------------------------------------------------------- launch
extern "C" void kernel_launch(void* const* d_in, const int* in_sizes, int n_in,
                              void* d_out, int out_size, void* d_ws, size_t ws_size,
                              hipStream_t stream) {
  (void)in_sizes; (void)n_in; (void)out_size; (void)ws_size;
  const float* X = (const float*)d_in[0];
  const float* Y = (const float*)d_in[1];
  const int* mask = (const int*)d_in[2];
  const float* Wq = (const float*)d_in[3];
  const float* bq = (const float*)d_in[4];
  const float* Wk = (const float*)d_in[5];
  const float* bk = (const float*)d_in[6];
  const float* Wv = (const float*)d_in[7];
  const float* bv = (const float*)d_in[8];
  const float* Wo = (const float*)d_in[9];
  const float* bo = (const float*)d_in[10];
  float* out = (float*)d_out;

  const float SC = 0.18033688011112042f;  // (1/sqrt(64)) * log2(e), folded into Wq/bq

  char* ws = (char*)d_ws;
  const size_t SZ = 16777216;  // 8192*1024*2B
  ushort* Xb = (ushort*)(ws);
  ushort* Yb = (ushort*)(ws + SZ);
  ushort* Qb = (ushort*)(ws + 2 * SZ);
  ushort* Kb = (ushort*)(ws + 3 * SZ);
  ushort* Vt = (ushort*)(ws + 4 * SZ);
  ushort* Cc = (ushort*)(ws + 5 * SZ);
  ushort* Wqb = (ushort*)(ws + 6 * SZ);
  ushort* Wkb = (ushort*)(ws + 6 * SZ + 2097152);
  ushort* Wvb = (ushort*)(ws + 6 * SZ + 2 * 2097152);
  ushort* Wob = (ushort*)(ws + 6 * SZ + 3 * 2097152);
  ushort* Mp  = (ushort*)(ws + 6 * SZ + 4 * 2097152);  // 2 MB packed mask

  cast_bf16_k<<<8192, 256, 0, stream>>>(X, Xb, 2097152, 1.0f);
  cast_bf16_k<<<8192, 256, 0, stream>>>(Y, Yb, 2097152, 1.0f);
  cast_bf16_k<<<1024, 256, 0, stream>>>(Wq, Wqb, 262144, SC);   // Q pre-scaled
  cast_bf16_k<<<1024, 256, 0, stream>>>(Wk, Wkb, 262144, 1.0f);
  cast_bf16_k<<<1024, 256, 0, stream>>>(Wv, Wvb, 262144, 1.0f);
  cast_bf16_k<<<1024, 256, 0, stream>>>(Wo, Wob, 262144, 1.0f);
  mask_pack_k<<<4096, 256, 0, stream>>>(mask, Mp, 1048576);

  gemm_bt<0><<<512, 256, 0, stream>>>(Xb, Wqb, bq, (void*)Qb, SC);
  gemm_bt<0><<<512, 256, 0, stream>>>(Yb, Wkb, bk, (void*)Kb, 1.0f);
  gemm_bt<1><<<512, 256, 0, stream>>>(Yb, Wvb, bv, (void*)Vt, 1.0f);

  attn_k<<<8192, 256, 0, stream>>>(Qb, Kb, Vt, Mp, out + 8388608, Cc);

  gemm_bt<2><<<512, 256, 0, stream>>>(Cc, Wob, bo, (void*)out, 1.0f);
}

// Round 8
// 796.597 us; speedup vs baseline: 1.9659x; 1.9659x over previous
//
#include <hip/hip_runtime.h>
#include <stdint.h>

typedef __attribute__((ext_vector_type(8))) short bf8_t;   // 8 bf16 (4 VGPRs) MFMA A/B frag
typedef __attribute__((ext_vector_type(4))) float f4_t;    // MFMA C/D frag

#define DEVI static __device__ __forceinline__

// fp32 -> bf16 round-to-nearest-even
DEVI unsigned short f2b(float f) {
  unsigned u = __builtin_bit_cast(unsigned, f);
  u += 0x7fffu + ((u >> 16) & 1u);
  return (unsigned short)(u >> 16);
}

DEVI float b2f(unsigned short v) {
  return __builtin_bit_cast(float, (unsigned)v << 16);
}

// ---------------------------------------------------------------- cast kernel (with optional scale fold)
__global__ void cast_bf16_k(const float* __restrict__ src, ushort* __restrict__ dst, int n4, float scale) {
  int i = blockIdx.x * 256 + threadIdx.x;
  if (i >= n4) return;
  float4 v = reinterpret_cast<const float4*>(src)[i];
  ushort4 o;
  o.x = f2b(v.x * scale); o.y = f2b(v.y * scale); o.z = f2b(v.z * scale); o.w = f2b(v.w * scale);
  reinterpret_cast<ushort4*>(dst)[i] = o;
}

// ---------------------------------------------------------------- mask bit-pack
// mask int32 (b,n,m) in {0,1}  ->  packed ushort words: word i covers cols i*16..i*16+15,
// bit j = mask[col i*16+j]. Total 4*2048*128 ushorts = 2 MB (L2-resident in attn).
__global__ void mask_pack_k(const int* __restrict__ mask, ushort* __restrict__ mp, int nwords) {
  int i = blockIdx.x * 256 + threadIdx.x;
  if (i >= nwords) return;
  const int4* src = reinterpret_cast<const int4*>(mask + (size_t)i * 16);
  unsigned v = 0;
#pragma unroll
  for (int j = 0; j < 4; j++) {
    int4 m = src[j];
    v |= ((unsigned)(m.x & 1) << (j * 4 + 0));
    v |= ((unsigned)(m.y & 1) << (j * 4 + 1));
    v |= ((unsigned)(m.z & 1) << (j * 4 + 2));
    v |= ((unsigned)(m.w & 1) << (j * 4 + 3));
  }
  mp[i] = (ushort)v;
}

// ---------------------------------------------------------------- GEMM: C[n][o] = sum_d A[n][d]*W[o][d] + bias[o]*bscale
template<int MODE>
__global__ __launch_bounds__(256, 3) void gemm_bt(const ushort* __restrict__ A,
                                                  const ushort* __restrict__ W,
                                                  const float* __restrict__ bias,
                                                  void* __restrict__ outp, float bscale) {
  // XOR-swizzled LDS tiles: row stride 64 bf16 (128B), unit (16B) u stored at u ^ (row&7)
  __shared__ ushort As[128 * 64];
  __shared__ ushort Ws[128 * 64];
  const int t = threadIdx.x;
  const int tileCol = blockIdx.x & 7;
  const int tileRow = blockIdx.x >> 3;
  const int rowBase = tileRow * 128;
  const int colBase = tileCol * 128;

  const int r32 = t >> 3;
  const int cu = t & 7;
  const int w = t >> 6;
  const int lane = t & 63;
  const int q = lane >> 4;
  const int c = lane & 15;
  const int wr = (w >> 1) * 64;
  const int wc = (w & 1) * 64;

  f4_t acc[4][4];
#pragma unroll
  for (int i = 0; i < 4; i++)
#pragma unroll
    for (int j = 0; j < 4; j++) acc[i][j] = (f4_t){0.f, 0.f, 0.f, 0.f};

  for (int k0 = 0; k0 < 1024; k0 += 64) {
#pragma unroll
    for (int rs = 0; rs < 4; rs++) {
      int r = rs * 32 + r32;
      int4 va = *reinterpret_cast<const int4*>(A + (size_t)(rowBase + r) * 1024 + k0 + cu * 8);
      int4 vw = *reinterpret_cast<const int4*>(W + (size_t)(colBase + r) * 1024 + k0 + cu * 8);
      *reinterpret_cast<int4*>(&As[r * 64 + ((cu ^ (r & 7)) << 3)]) = va;
      *reinterpret_cast<int4*>(&Ws[r * 64 + ((cu ^ (r & 7)) << 3)]) = vw;
    }
    __syncthreads();
    bf8_t af[4][2], bfr[4][2];
#pragma unroll
    for (int i = 0; i < 4; i++) {
      int ra = wr + i * 16 + c;
      int rb = wc + i * 16 + c;
#pragma unroll
      for (int s = 0; s < 2; s++) {
        af[i][s] = *reinterpret_cast<const bf8_t*>(&As[ra * 64 + (((s * 4 + q) ^ (ra & 7)) << 3)]);
        bfr[i][s] = *reinterpret_cast<const bf8_t*>(&Ws[rb * 64 + (((s * 4 + q) ^ (rb & 7)) << 3)]);
      }
    }
#pragma unroll
    for (int i = 0; i < 4; i++)
#pragma unroll
      for (int j = 0; j < 4; j++) {
        acc[i][j] = __builtin_amdgcn_mfma_f32_16x16x32_bf16(af[i][0], bfr[j][0], acc[i][j], 0, 0, 0);
        acc[i][j] = __builtin_amdgcn_mfma_f32_16x16x32_bf16(af[i][1], bfr[j][1], acc[i][j], 0, 0, 0);
      }
    __syncthreads();
  }

  // epilogue: D layout col=lane&15, row=(lane>>4)*4+reg  [measured m89/m91]
#pragma unroll
  for (int j = 0; j < 4; j++) {
    int col = colBase + wc + j * 16 + c;
    float bj = bias[col] * bscale;
#pragma unroll
    for (int i = 0; i < 4; i++) {
      int rbase = rowBase + wr + i * 16 + q * 4;
      if (MODE == 0) {
        ushort* out = (ushort*)outp;
#pragma unroll
        for (int reg = 0; reg < 4; reg++)
          out[(size_t)(rbase + reg) * 1024 + col] = f2b(acc[i][j][reg] + bj);
      } else if (MODE == 1) {
        ushort* out = (ushort*)outp;
        int bb = rbase >> 11;
        int nl = rbase & 2047;
        ushort4 v;
        v.x = f2b(acc[i][j][0] + bj);
        v.y = f2b(acc[i][j][1] + bj);
        v.z = f2b(acc[i][j][2] + bj);
        v.w = f2b(acc[i][j][3] + bj);
        *reinterpret_cast<ushort4*>(out + ((size_t)(bb * 1024 + col) * 2048 + nl)) = v;
      } else {
        float* out = (float*)outp;
#pragma unroll
        for (int reg = 0; reg < 4; reg++)
          out[(size_t)(rbase + reg) * 1024 + col] = acc[i][j][reg] + bj;
      }
    }
  }
}

// ---------------------------------------------------------------- fused attention: P staged in LDS
// Block: one (b,h), 16 q-rows, 512 threads; 8 waves x 256-col m-strips.
// Q PRE-SCALED by (1/sqrt(64))*log2(e) -> exp2(s) is the softmax numerator.
// R1-R7 lessons: (a) per-lane e-state arrays (32-64 VGPRs) get SPILLED (0.3-1 GB scratch);
// (b) per-chunk __threadfence_block (= s_waitcnt vmcnt(0)) serializes all load latency;
// (c) fence removal + big unrolls -> scheduler hoists loads -> spill again.
// Fix: stage unnormalized P (bf16) for the whole block in 64KB of XOR-swizzled LDS.
//   pass 1: QK sweep writes P_lds (scalar, same as old per-chunk Pb) + accumulates l.
//   pass 2a: PV reads A-frags from P_lds (ds_read_b128, swizzle -> no 16-way conflict).
//   pass 2b: beta = P*(1/l) read back VECTORIZED (bf16x8) and stored as 2xfloat4
//            (1KB contiguous per wave-instr vs 64B scattered segments before).
//   Ow merge reuses the P_lds space (union) after a barrier.
// Per-lane state ~20 regs + transients; short runtime loops (unroll 2) bound hoisting.
__global__ __launch_bounds__(512, 4) void attn_k(const ushort* __restrict__ Qb,
                                                 const ushort* __restrict__ Kb,
                                                 const ushort* __restrict__ Vt,
                                                 const ushort* __restrict__ Mp,
                                                 float* __restrict__ beta,
                                                 ushort* __restrict__ Cc) {
  __shared__ ushort Pl[8 * 16 * 256];  // 64KB: P strips [w][16 rows][256 cols], 16B-unit swizzled
  __shared__ float lpart[8][16];
  float* OwU = (float*)Pl;             // union: Ow[8][16][68] after P consumed

  // XCD-affine swizzle: head-pairs pinned to XCD so K/V stay L2-resident
  const int L = blockIdx.x;
  const int bh = (L >> 10) * 8 + (L & 7);  // 0..63
  const int qt = (L >> 3) & 127;
  const int b = bh >> 4;
  const int h = bh & 15;
  const int n0 = qt * 16;

  const int t = threadIdx.x;
  const int w = t >> 6;    // 0..7
  const int lane = t & 63;
  const int q = lane >> 4;
  const int c = lane & 15;

  const size_t qbase = ((size_t)(b * 2048 + n0 + c)) * 1024 + h * 64 + q * 8;
  bf8_t qa0 = *reinterpret_cast<const bf8_t*>(Qb + qbase);
  bf8_t qa1 = *reinterpret_cast<const bf8_t*>(Qb + qbase + 32);

  const int mBase = w * 256;
  const size_t kbase0 = ((size_t)(b * 2048 + mBase + c)) * 1024 + h * 64 + q * 8;
  const ushort* mpk = Mp + ((size_t)(b * 2048 + n0)) * 128 + (mBase >> 4);
  ushort* Ps = Pl + w * (16 * 256);  // this wave's strip

  // ---- pass 1: QK sweep, e -> LDS strip, accumulate l  (no fences, short runtime loop)
  float ls[4] = {0.f, 0.f, 0.f, 0.f};
#pragma unroll 2
  for (int mb = 0; mb < 16; ++mb) {
    const ushort* kp = Kb + kbase0 + (size_t)mb * 16 * 1024;
    bf8_t k0 = *reinterpret_cast<const bf8_t*>(kp);
    bf8_t k1 = *reinterpret_cast<const bf8_t*>(kp + 32);
    f4_t s = (f4_t){0.f, 0.f, 0.f, 0.f};
    s = __builtin_amdgcn_mfma_f32_16x16x32_bf16(qa0, k0, s, 0, 0, 0);
    s = __builtin_amdgcn_mfma_f32_16x16x32_bf16(qa1, k1, s, 0, 0, 0);
    const int u = mb * 2 + (c >> 3);
#pragma unroll
    for (int reg = 0; reg < 4; reg++) {
      const int row = q * 4 + reg;
      unsigned mw = mpk[(size_t)row * 128 + mb];  // broadcast across 16 lanes
      float e = ((mw >> c) & 1u) ? 0.f : __builtin_amdgcn_exp2f(s[reg]);
      ls[reg] += e;
      Ps[row * 256 + (((u ^ (row & 7)) << 3) | (c & 7))] = f2b(e);
    }
  }

  // ---- l reduce -> lpart
#pragma unroll
  for (int reg = 0; reg < 4; reg++) {
    ls[reg] += __shfl_xor(ls[reg], 1);
    ls[reg] += __shfl_xor(ls[reg], 2);
    ls[reg] += __shfl_xor(ls[reg], 4);
    ls[reg] += __shfl_xor(ls[reg], 8);
  }
  if (c == 0) {
#pragma unroll
    for (int reg = 0; reg < 4; reg++) lpart[w][q * 4 + reg] = ls[reg];
  }
  __syncthreads();  // P strips + lpart visible to all

  // ---- pass 2a: PV from own LDS strip (unnormalized); V loads free to pipeline
  f4_t o[4];
#pragma unroll
  for (int db = 0; db < 4; db++) o[db] = (f4_t){0.f, 0.f, 0.f, 0.f};
  const size_t vbase = ((size_t)(b * 1024 + h * 64 + c)) * 2048 + mBase + q * 8;
#pragma unroll 2
  for (int p = 0; p < 8; ++p) {
    const int u = p * 4 + q;
    bf8_t pa = *reinterpret_cast<const bf8_t*>(&Ps[c * 256 + ((u ^ (c & 7)) << 3)]);
    const int m0 = p * 32;
#pragma unroll
    for (int db = 0; db < 4; db++) {
      bf8_t vf = *reinterpret_cast<const bf8_t*>(Vt + vbase + (size_t)db * 16 * 2048 + m0);
      o[db] = __builtin_amdgcn_mfma_f32_16x16x32_bf16(pa, vf, o[db], 0, 0, 0);
    }
  }

  // ---- pass 2b: beta = P * (1/l), vectorized: thread t -> row r=t>>5, unit j=t&31
  {
    const int r = t >> 5;
    const int j = t & 31;
    float lsum = 0.f;
#pragma unroll
    for (int ww = 0; ww < 8; ww++) lsum += lpart[ww][r];
    const float li = 1.0f / lsum;
    float* brow = beta + ((size_t)(bh * 2048 + n0 + r)) * 2048;
#pragma unroll
    for (int i = 0; i < 8; ++i) {  // strip i holds cols i*256..i*256+255
      bf8_t pv = *reinterpret_cast<const bf8_t*>(&Pl[(i * 16 + r) * 256 + ((j ^ (r & 7)) << 3)]);
      float4 f0, f1;
      f0.x = b2f((unsigned short)pv[0]) * li;
      f0.y = b2f((unsigned short)pv[1]) * li;
      f0.z = b2f((unsigned short)pv[2]) * li;
      f0.w = b2f((unsigned short)pv[3]) * li;
      f1.x = b2f((unsigned short)pv[4]) * li;
      f1.y = b2f((unsigned short)pv[5]) * li;
      f1.z = b2f((unsigned short)pv[6]) * li;
      f1.w = b2f((unsigned short)pv[7]) * li;
      float* dst = brow + i * 256 + j * 8;
      *reinterpret_cast<float4*>(dst) = f0;
      *reinterpret_cast<float4*>(dst + 4) = f1;
    }
  }

  __syncthreads();  // all P reads (PV + beta) done -> safe to overwrite with Ow

  // ---- merge O across 8 waves via union region, scale by 1/l, store concat bf16
#pragma unroll
  for (int db = 0; db < 4; db++)
#pragma unroll
    for (int reg = 0; reg < 4; reg++)
      OwU[(w * 16 + q * 4 + reg) * 68 + db * 16 + c] = o[db][reg];
  __syncthreads();
  if (t < 256) {
    int r = t >> 4;
    int d0 = (t & 15) * 4;
    float lsum = 0.f;
#pragma unroll
    for (int ww = 0; ww < 8; ww++) lsum += lpart[ww][r];
    float sl = 1.0f / lsum;
    float4 acc = (float4){0.f, 0.f, 0.f, 0.f};
#pragma unroll
    for (int ww = 0; ww < 8; ww++) {
      float4 sv = *reinterpret_cast<const float4*>(&OwU[(ww * 16 + r) * 68 + d0]);
      acc.x += sv.x; acc.y += sv.y; acc.z += sv.z; acc.w += sv.w;
    }
    ushort4 ov;
    ov.x = f2b(acc.x * sl);
    ov.y = f2b(acc.y * sl);
    ov.z = f2b(acc.z * sl);
    ov.w = f2b(acc.w * sl);
    *reinterpret_cast<ushort4*>(Cc + ((size_t)(b * 2048 + n0 + r)) * 1024 + h * 64 + d0) = ov;
  }
}

// ---------------------------------------------------------------- launch
extern "C" void kernel_launch(void* const* d_in, const int* in_sizes, int n_in,
                              void* d_out, int out_size, void* d_ws, size_t ws_size,
                              hipStream_t stream) {
  (void)in_sizes; (void)n_in; (void)out_size; (void)ws_size;
  const float* X = (const float*)d_in[0];
  const float* Y = (const float*)d_in[1];
  const int* mask = (const int*)d_in[2];
  const float* Wq = (const float*)d_in[3];
  const float* bq = (const float*)d_in[4];
  const float* Wk = (const float*)d_in[5];
  const float* bk = (const float*)d_in[6];
  const float* Wv = (const float*)d_in[7];
  const float* bv = (const float*)d_in[8];
  const float* Wo = (const float*)d_in[9];
  const float* bo = (const float*)d_in[10];
  float* out = (float*)d_out;

  const float SC = 0.18033688011112042f;  // (1/sqrt(64)) * log2(e), folded into Wq/bq

  char* ws = (char*)d_ws;
  const size_t SZ = 16777216;  // 8192*1024*2B
  ushort* Xb = (ushort*)(ws);
  ushort* Yb = (ushort*)(ws + SZ);
  ushort* Qb = (ushort*)(ws + 2 * SZ);
  ushort* Kb = (ushort*)(ws + 3 * SZ);
  ushort* Vt = (ushort*)(ws + 4 * SZ);
  ushort* Cc = (ushort*)(ws + 5 * SZ);
  ushort* Wqb = (ushort*)(ws + 6 * SZ);
  ushort* Wkb = (ushort*)(ws + 6 * SZ + 2097152);
  ushort* Wvb = (ushort*)(ws + 6 * SZ + 2 * 2097152);
  ushort* Wob = (ushort*)(ws + 6 * SZ + 3 * 2097152);
  ushort* Mp  = (ushort*)(ws + 6 * SZ + 4 * 2097152);  // 2 MB packed mask

  cast_bf16_k<<<8192, 256, 0, stream>>>(X, Xb, 2097152, 1.0f);
  cast_bf16_k<<<8192, 256, 0, stream>>>(Y, Yb, 2097152, 1.0f);
  cast_bf16_k<<<1024, 256, 0, stream>>>(Wq, Wqb, 262144, SC);   // Q pre-scaled
  cast_bf16_k<<<1024, 256, 0, stream>>>(Wk, Wkb, 262144, 1.0f);
  cast_bf16_k<<<1024, 256, 0, stream>>>(Wv, Wvb, 262144, 1.0f);
  cast_bf16_k<<<1024, 256, 0, stream>>>(Wo, Wob, 262144, 1.0f);
  mask_pack_k<<<4096, 256, 0, stream>>>(mask, Mp, 1048576);

  gemm_bt<0><<<512, 256, 0, stream>>>(Xb, Wqb, bq, (void*)Qb, SC);
  gemm_bt<0><<<512, 256, 0, stream>>>(Yb, Wkb, bk, (void*)Kb, 1.0f);
  gemm_bt<1><<<512, 256, 0, stream>>>(Yb, Wvb, bv, (void*)Vt, 1.0f);

  attn_k<<<8192, 512, 0, stream>>>(Qb, Kb, Vt, Mp, out + 8388608, Cc);

  gemm_bt<2><<<512, 256, 0, stream>>>(Cc, Wob, bo, (void*)out, 1.0f);
}